// Round 9
// baseline (225.477 us; speedup 1.0000x reference)
//
#include <hip/hip_runtime.h>

// OmniShift collapsed to one effective 5x5 depthwise conv per channel.
// x: (8, 192, 256, 256) fp32. 805 MB min traffic -> ~128us @6.3TB/s copy rate.
//
// R9 = R8 + readfirstlane fix. R8's __builtin_amdgcn_readfirstlane(float)
// implicitly CONVERTED float->int (fptosi), truncating all weights to ~0.
// Now bit_cast through int. Rest identical: max-occupancy pipelined ring.
//  - 16-slot x 260 LDS ring (16.6 KB) -> 8 blocks/CU; 32 waves/CU.
//  - VGPR<=64 via __launch_bounds__(256,8): 2 output rows/thread streamed
//    from 6 LDS window rows into dual accumulators; weights in SGPRs.
//  - 6144 64-row bands, 3 per block -> 2048 blocks = 8/CU exactly, no tail.
//  - Per phase: prefetch->regs, compute, [lgkm;barrier], ds_write, stores,
//    [lgkm;barrier]. vmcnt never drained at barriers.

typedef float f32x4 __attribute__((ext_vector_type(4)));

constexpr int Bn = 8, Cn = 192, Hn = 256, Wn = 256;
constexpr int BAND    = 64;          // rows per band (work item)
constexpr int PH      = 8;           // rows per phase
constexpr int NPH     = BAND / PH;   // 8
constexpr int SLOTS   = 16;          // ring rows; slot(rr) = (rr + 2) & 15
constexpr int LSTRIDE = 260;         // 2 + 256 + 2
constexpr int NBANDS  = Bn * Cn * (Hn / BAND);   // 6144
constexpr int NBLK    = NBANDS / 3;              // 2048 = 8 blocks/CU exactly

__device__ __forceinline__ float uniformf(float v) {
    return __builtin_bit_cast(float,
        __builtin_amdgcn_readfirstlane(__builtin_bit_cast(int, v)));
}

__global__ __launch_bounds__(256, 8)
void omnishift_kernel(const float* __restrict__ x,
                      const float* __restrict__ w1,
                      const float* __restrict__ w3,
                      const float* __restrict__ w5,
                      const float* __restrict__ alpha,
                      float* __restrict__ out)
{
    __shared__ float lds[SLOTS * LSTRIDE];   // 16640 B -> 8 blocks/CU

    const int tid = threadIdx.x;
    const int ct  = tid & 63;    // column group: cols 4ct..4ct+3
    const int rg  = tid >> 6;    // wave id 0..3

    // zero side halo cols of all 16 slots once (never rewritten)
    if (tid < SLOTS * 4) {
        const int r   = tid >> 2;
        const int q   = tid & 3;
        const int col = (q < 2) ? q : (256 + q);   // 0,1,258,259
        lds[r * LSTRIDE + col] = 0.f;
    }

#pragma unroll 1
    for (int ib = 0; ib < 3; ++ib) {
        const int w     = blockIdx.x * 3 + ib;   // band id; consecutive -> seam L2 reuse
        const int plane = w >> 2;                // b*C + c
        const int band  = w & 3;
        const int r0    = band * BAND;
        const int c     = plane % Cn;

        // ---- effective 5x5 weights -> SGPRs (uniform across wave) ----
        const float a0 = alpha[0], a1 = alpha[1], a2 = alpha[2], a3 = alpha[3];
        float wfs[5][5];
#pragma unroll
        for (int i = 0; i < 5; ++i)
#pragma unroll
            for (int j = 0; j < 5; ++j) {
                float v = a3 * w5[(c * 5 + i) * 5 + j];
                if (i >= 1 && i <= 3 && j >= 1 && j <= 3)
                    v += a2 * w3[(c * 3 + (i - 1)) * 3 + (j - 1)];
                if (i == 2 && j == 2)
                    v += a1 * w1[c] + a0;
                wfs[i][j] = uniformf(v);
            }

        const float* xp = x   + (size_t)plane * (Hn * Wn);
        float*       op = out + (size_t)plane * (Hn * Wn);

        // ---- prologue: band rows -2..9 -> slots 0..11 (3 f32x4 per thread) ----
        // (previous band's last-phase step-3 barrier already drained ring reads)
#pragma unroll
        for (int i = 0; i < 3; ++i) {
            const int idx = tid + i * 256;       // 12 rows * 64
            const int row = idx >> 6;            // wave-uniform
            const int l   = idx & 63;
            const int gr  = r0 + row - 2;
            f32x4 v = {0.f, 0.f, 0.f, 0.f};
            if ((unsigned)gr < (unsigned)Hn)
                v = *reinterpret_cast<const f32x4*>(xp + (size_t)gr * Wn + 4 * l);
            float* dst = &lds[row * LSTRIDE + 2 + 4 * l];
            dst[0] = v.x; dst[1] = v.y; dst[2] = v.z; dst[3] = v.w;
        }
        __syncthreads();

        auto phase = [&](const int p, const int sbase) {   // sbase = (8p)&15: literal 0/8
            // -- 1) issue prefetch: band rows 8p+10..8p+17 -> regs --
            f32x4 st0 = {0.f,0.f,0.f,0.f}, st1 = {0.f,0.f,0.f,0.f};
            if (p < NPH - 1) {
                const int gr0 = r0 + PH * p + 10 + rg;       // wave-uniform
                const int gr1 = gr0 + 4;
                if (gr0 < Hn) st0 = *reinterpret_cast<const f32x4*>(xp + (size_t)gr0 * Wn + 4 * ct);
                if (gr1 < Hn) st1 = *reinterpret_cast<const f32x4*>(xp + (size_t)gr1 * Wn + 4 * ct);
            }

            // -- 2) compute output rows A=8p+2rg, A+1 from 6 LDS window rows --
            f32x4 accA = {0.f,0.f,0.f,0.f}, accB = {0.f,0.f,0.f,0.f};
#pragma unroll
            for (int off = 0; off < 6; ++off) {
                const int slot = (sbase + 2 * rg + off) & (SLOTS - 1);
                const float* src = &lds[slot * LSTRIDE + 4 * ct];  // 16B aligned
                float rw[8];
#pragma unroll
                for (int j = 0; j < 8; ++j) rw[j] = src[j];        // 2x ds_read_b128
                if (off <= 4) {
#pragma unroll
                    for (int d = 0; d < 5; ++d)
#pragma unroll
                        for (int j = 0; j < 4; ++j)
                            accA[j] += rw[j + d] * wfs[off][d];
                }
                if (off >= 1) {
#pragma unroll
                    for (int d = 0; d < 5; ++d)
#pragma unroll
                        for (int j = 0; j < 4; ++j)
                            accB[j] += rw[j + d] * wfs[off - 1][d];
                }
            }

            // -- 3) ring reads done -> allow overwrite of oldest slots --
            asm volatile("s_waitcnt lgkmcnt(0)\n\ts_barrier" ::: "memory");

            // -- 4) ds_write staged rows (slots (sbase+12+rg) and +4, &15) --
            if (p < NPH - 1) {
                const int s0 = (sbase + 12 + rg) & (SLOTS - 1);
                const int s1 = (sbase + 12 + rg + 4) & (SLOTS - 1);
                float* d0 = &lds[s0 * LSTRIDE + 2 + 4 * ct];
                float* d1 = &lds[s1 * LSTRIDE + 2 + 4 * ct];
                d0[0] = st0.x; d0[1] = st0.y; d0[2] = st0.z; d0[3] = st0.w;
                d1[0] = st1.x; d1[1] = st1.y; d1[2] = st1.z; d1[3] = st1.w;
            }

            // -- 5) output stores (vmcnt never drained for these) --
            float* outp = op + (size_t)(r0 + PH * p + 2 * rg) * Wn + 4 * ct;
            *reinterpret_cast<f32x4*>(outp)      = accA;
            *reinterpret_cast<f32x4*>(outp + Wn) = accB;

            // -- 6) ring writes visible before next phase's reads --
            if (p < NPH - 1)
                asm volatile("s_waitcnt lgkmcnt(0)\n\ts_barrier" ::: "memory");
        };

#pragma unroll 1
        for (int pp = 0; pp < NPH / 2; ++pp) {
            phase(2 * pp,     0);    // (8*(2pp))   & 15 = 0
            phase(2 * pp + 1, 8);    // (8*(2pp+1)) & 15 = 8
        }
    }
}

extern "C" void kernel_launch(void* const* d_in, const int* in_sizes, int n_in,
                              void* d_out, int out_size, void* d_ws, size_t ws_size,
                              hipStream_t stream)
{
    const float* x     = (const float*)d_in[0];
    const float* w1    = (const float*)d_in[1];
    const float* w3    = (const float*)d_in[2];
    const float* w5    = (const float*)d_in[3];
    const float* alpha = (const float*)d_in[4];
    float* out = (float*)d_out;

    omnishift_kernel<<<NBLK, 256, 0, stream>>>(x, w1, w3, w5, alpha, out);
}

// Round 10
// 221.544 us; speedup vs baseline: 1.0178x; 1.0178x over previous
//
#include <hip/hip_runtime.h>
#include <hip/hip_bf16.h>

// OmniShift collapsed to one effective 5x5 depthwise conv per channel.
// x: (8, 192, 256, 256) fp32. 805 MB min traffic.
//
// R10: clean occupancy test. All fast variants (156-158us) ran at 16 waves/CU;
// R6 showed fetch reduction alone doesn't help -> latency/MLP-limited, not BW.
// This kernel: bf16 LDS ring (16.6 KB, 32 slots pow2) + launch_bounds(256,6)
// (VGPR budget 85 for ~45 live - no R9-style spill) -> >=24 waves/CU.
// One barrier per phase (12-slot staging margin spans 3 phases).

typedef float f32x4 __attribute__((ext_vector_type(4)));

constexpr int Bn = 8, Cn = 192, Hn = 256, Wn = 256;
constexpr int BAND    = 128;         // rows per block
constexpr int PH      = 8;           // rows per phase
constexpr int NPH     = BAND / PH;   // 16
constexpr int SLOTS   = 32;          // ring rows; slot(rr) = (rr + 2) & 31
constexpr int LSTRIDE = 260;         // bf16 elems: 2 + 256 + 2
constexpr int NBLK    = Bn * Cn * (Hn / BAND);   // 3072 = 2 rounds @ 6/CU

__device__ __forceinline__ float uniformf(float v) {
    return __builtin_bit_cast(float,
        __builtin_amdgcn_readfirstlane(__builtin_bit_cast(int, v)));
}
__device__ __forceinline__ unsigned pack2(float f0, float f1) {   // RNE via HW cvt
    unsigned short l = __builtin_bit_cast(unsigned short, __float2bfloat16(f0));
    unsigned short h = __builtin_bit_cast(unsigned short, __float2bfloat16(f1));
    return (unsigned)l | ((unsigned)h << 16);
}

__global__ __launch_bounds__(256, 6)
void omnishift_kernel(const float* __restrict__ x,
                      const float* __restrict__ w1,
                      const float* __restrict__ w3,
                      const float* __restrict__ w5,
                      const float* __restrict__ alpha,
                      float* __restrict__ out)
{
    __shared__ unsigned short lds[SLOTS * LSTRIDE];   // 16640 B

    const int tid   = threadIdx.x;
    const int ct    = tid & 63;    // column group: cols 4ct..4ct+3
    const int rg    = tid >> 6;    // wave id 0..3
    const int band  = blockIdx.x & 1;
    const int plane = blockIdx.x >> 1;   // b*C + c
    const int r0    = band * BAND;
    const int c     = plane % Cn;

    // ---- effective 5x5 weights -> SGPRs ----
    const float a0 = alpha[0], a1 = alpha[1], a2 = alpha[2], a3 = alpha[3];
    float wfs[5][5];
#pragma unroll
    for (int i = 0; i < 5; ++i)
#pragma unroll
        for (int j = 0; j < 5; ++j) {
            float v = a3 * w5[(c * 5 + i) * 5 + j];
            if (i >= 1 && i <= 3 && j >= 1 && j <= 3)
                v += a2 * w3[(c * 3 + (i - 1)) * 3 + (j - 1)];
            if (i == 2 && j == 2)
                v += a1 * w1[c] + a0;
            wfs[i][j] = uniformf(v);
        }

    const float* xp = x   + (size_t)plane * (Hn * Wn);
    float*       op = out + (size_t)plane * (Hn * Wn);

    // ---- zero side-halo cols (padded cols 0,1,258,259) of all slots ----
    if (tid < SLOTS * 4) {
        const int r   = tid >> 2;
        const int q   = tid & 3;
        const int col = (q < 2) ? q : (256 + q);
        lds[r * LSTRIDE + col] = 0;
    }

    // ---- prologue: band rows -2..9 -> slots 0..11 ----
#pragma unroll
    for (int i = 0; i < 3; ++i) {
        const int idx = tid + i * 256;        // 12 rows * 64 f32x4
        const int row = idx >> 6;             // 0..11 (slot = row)
        const int l   = idx & 63;
        const int gr  = r0 + row - 2;
        f32x4 v = {0.f, 0.f, 0.f, 0.f};
        if ((unsigned)gr < (unsigned)Hn)
            v = *reinterpret_cast<const f32x4*>(xp + (size_t)gr * Wn + 4 * l);
        unsigned* dst = reinterpret_cast<unsigned*>(&lds[row * LSTRIDE + 2 + 4 * l]);
        dst[0] = pack2(v.x, v.y);             // 2x ds_write_b32 (addr = 4 mod 8)
        dst[1] = pack2(v.z, v.w);
    }
    __syncthreads();

    // phase: output rows 8p+2rg, +1; window = ring rows 8p+2rg-2 .. +3
    auto phase = [&](const int p, const int sbase) {   // sbase = (8p)&31 literal
        // -- 1) issue prefetch: band rows 8p+10+2rg, +1 -> regs --
        f32x4 st0 = {0.f,0.f,0.f,0.f}, st1 = {0.f,0.f,0.f,0.f};
        if (p < NPH - 1) {
            const int gr0 = r0 + PH * p + 10 + 2 * rg;   // wave-uniform
            if (gr0 < Hn)     st0 = *reinterpret_cast<const f32x4*>(xp + (size_t)gr0 * Wn + 4 * ct);
            if (gr0 + 1 < Hn) st1 = *reinterpret_cast<const f32x4*>(xp + (size_t)(gr0 + 1) * Wn + 4 * ct);
        }

        // -- 2) compute: stream 6 window rows from ring, dual accumulate --
        f32x4 accA = {0.f,0.f,0.f,0.f}, accB = {0.f,0.f,0.f,0.f};
#pragma unroll
        for (int off = 0; off < 6; ++off) {
            const int slot = (sbase + 2 * rg + off) & (SLOTS - 1);
            // 8 padded cols 4ct..4ct+7 = input cols 4ct-2..4ct+5; byte 8ct: 8-aligned
            const uint2* src = reinterpret_cast<const uint2*>(&lds[slot * LSTRIDE + 4 * ct]);
            const uint2 u0 = src[0], u1 = src[1];        // 2x ds_read_b64
            float rw[8];
            rw[0] = __builtin_bit_cast(float, u0.x << 16);
            rw[1] = __builtin_bit_cast(float, u0.x & 0xffff0000u);
            rw[2] = __builtin_bit_cast(float, u0.y << 16);
            rw[3] = __builtin_bit_cast(float, u0.y & 0xffff0000u);
            rw[4] = __builtin_bit_cast(float, u1.x << 16);
            rw[5] = __builtin_bit_cast(float, u1.x & 0xffff0000u);
            rw[6] = __builtin_bit_cast(float, u1.y << 16);
            rw[7] = __builtin_bit_cast(float, u1.y & 0xffff0000u);
            if (off <= 4) {
#pragma unroll
                for (int d = 0; d < 5; ++d)
#pragma unroll
                    for (int j = 0; j < 4; ++j)
                        accA[j] += rw[j + d] * wfs[off][d];
            }
            if (off >= 1) {
#pragma unroll
                for (int d = 0; d < 5; ++d)
#pragma unroll
                    for (int j = 0; j < 4; ++j)
                        accB[j] += rw[j + d] * wfs[off - 1][d];
            }
        }

        // -- 3) pack staged rows -> ring (slots (sbase+12+2rg), +1) --
        //    (overwrites slots last read 3 phases ago -> safe under 1 barrier/phase)
        if (p < NPH - 1) {
            const int s0 = (sbase + 12 + 2 * rg) & (SLOTS - 1);
            const int s1 = (sbase + 13 + 2 * rg) & (SLOTS - 1);
            unsigned* d0 = reinterpret_cast<unsigned*>(&lds[s0 * LSTRIDE + 2 + 4 * ct]);
            unsigned* d1 = reinterpret_cast<unsigned*>(&lds[s1 * LSTRIDE + 2 + 4 * ct]);
            d0[0] = pack2(st0.x, st0.y);  d0[1] = pack2(st0.z, st0.w);
            d1[0] = pack2(st1.x, st1.y);  d1[1] = pack2(st1.z, st1.w);
        }

        // -- 4) output stores --
        float* outp = op + (size_t)(r0 + PH * p + 2 * rg) * Wn + 4 * ct;
        *reinterpret_cast<f32x4*>(outp)      = accA;
        *reinterpret_cast<f32x4*>(outp + Wn) = accB;

        // -- 5) single barrier: ring writes visible; vmcnt NOT drained --
        if (p < NPH - 1)
            asm volatile("s_waitcnt lgkmcnt(0)\n\ts_barrier" ::: "memory");
    };

#pragma unroll 1
    for (int pp = 0; pp < NPH / 4; ++pp) {
        phase(4 * pp + 0, 0);     // (8p)&31 for p=4k+0,1,2,3
        phase(4 * pp + 1, 8);
        phase(4 * pp + 2, 16);
        phase(4 * pp + 3, 24);
    }
}

extern "C" void kernel_launch(void* const* d_in, const int* in_sizes, int n_in,
                              void* d_out, int out_size, void* d_ws, size_t ws_size,
                              hipStream_t stream)
{
    const float* x     = (const float*)d_in[0];
    const float* w1    = (const float*)d_in[1];
    const float* w3    = (const float*)d_in[2];
    const float* w5    = (const float*)d_in[3];
    const float* alpha = (const float*)d_in[4];
    float* out = (float*)d_out;

    omnishift_kernel<<<NBLK, 256, 0, stream>>>(x, w1, w3, w5, alpha, out);
}

// Round 11
// 151.015 us; speedup vs baseline: 1.4931x; 1.4670x over previous
//
#include <hip/hip_runtime.h>

// OmniShift collapsed to one effective 5x5 depthwise conv per channel.
// x: (8, 192, 256, 256) fp32. 805 MB min traffic -> ~128us @ copy-ubench rate.
//
// R11 = R1 structure (36-row tile, stage-all -> syncthreads -> compute-all,
// 12288 blocks, f32, no swizzle) with staging via global_load_lds width=16
// (HBM->LDS DMA: no dest VGPRs, no vmcnt->ds_write chain, 9 DMAs in flight).
// Tests: is the 157us plateau staging-MLP-bound or byte-bound?
//  - LDS row = 264 f32: left pad 4 -> DMA dest base 16B-aligned; halo zeros at
//    pos {2,3,260,261}; window reads 4x ds_read_b64 at pos c0+2 (8-aligned).
//  - OOB rows (wave-uniform): explicit zero ds_write instead of DMA.
// Lesson R5/R9/R10: NEVER pass a min-waves arg to __launch_bounds__ here --
// allocator squeeze -> scratch spills (VGPR 64/32/40) dominated all costs.

typedef float f32x2 __attribute__((ext_vector_type(2)));
typedef float f32x4 __attribute__((ext_vector_type(4)));

constexpr int Bn = 8, Cn = 192, Hn = 256, Wn = 256;
constexpr int TR      = 32;          // output rows per block
constexpr int LROWS   = TR + 4;      // 36 staged rows
constexpr int LSTRIDE = 264;         // 4 + 256 + 4 f32; data col w at pos w+4
constexpr int BANDS   = Hn / TR;     // 8
constexpr int NWG     = Bn * Cn * BANDS;   // 12288

__device__ __forceinline__ float uniformf(float v) {
    return __builtin_bit_cast(float,
        __builtin_amdgcn_readfirstlane(__builtin_bit_cast(int, v)));
}

__device__ __forceinline__ void gload16(const float* g, float* l) {
    __builtin_amdgcn_global_load_lds(
        (const __attribute__((address_space(1))) unsigned int*)g,
        (__attribute__((address_space(3))) unsigned int*)l, 16, 0, 0);
}

__global__ __launch_bounds__(256)
void omnishift_kernel(const float* __restrict__ x,
                      const float* __restrict__ w1,
                      const float* __restrict__ w3,
                      const float* __restrict__ w5,
                      const float* __restrict__ alpha,
                      float* __restrict__ out)
{
    __shared__ float lds[LROWS * LSTRIDE];   // 38016 B -> 4 blocks/CU

    const int tid   = threadIdx.x;
    const int band  = blockIdx.x % BANDS;
    const int plane = blockIdx.x / BANDS;    // b*C + c
    const int c     = plane % Cn;
    const int r0    = band * TR;

    // ---- effective 5x5 weights (block-uniform -> SGPRs) ----
    const float a0 = alpha[0], a1 = alpha[1], a2 = alpha[2], a3 = alpha[3];
    float wf[5][5];
#pragma unroll
    for (int i = 0; i < 5; ++i)
#pragma unroll
        for (int j = 0; j < 5; ++j) {
            float v = a3 * w5[(c * 5 + i) * 5 + j];
            if (i >= 1 && i <= 3 && j >= 1 && j <= 3)
                v += a2 * w3[(c * 3 + (i - 1)) * 3 + (j - 1)];
            if (i == 2 && j == 2)
                v += a1 * w1[c] + a0;
            wf[i][j] = uniformf(v);
        }

    const float* xp = x + (size_t)plane * (Hn * Wn);

    // ---- zero halo cols: pos 2,3 (cols -2,-1), 260,261 (cols 256,257) ----
    if (tid < LROWS * 4) {
        const int r   = tid >> 2;
        const int q   = tid & 3;
        const int pos = (q < 2) ? (2 + q) : (258 + q);
        lds[r * LSTRIDE + pos] = 0.f;
    }

    // ---- stage 36 rows via HBM->LDS DMA (9 issues/thread, no dest regs) ----
#pragma unroll
    for (int i = 0; i < 9; ++i) {
        const int idx = tid + i * 256;       // 0..2303 = 36 rows * 64 lanes
        const int row = idx >> 6;            // wave-uniform
        const int l   = idx & 63;            // lane id
        const int gr  = r0 - 2 + row;
        float* dst = &lds[row * LSTRIDE + 4];         // uniform base; HW adds lane*16
        if ((unsigned)gr < (unsigned)Hn) {
            gload16(xp + (size_t)gr * Wn + 4 * l, dst);
        } else {
            f32x2 z = {0.f, 0.f};
            f32x2* d = reinterpret_cast<f32x2*>(dst + 4 * l);
            d[0] = z; d[1] = z;
        }
    }
    __syncthreads();   // compiler emits vmcnt(0) lgkmcnt(0) -> DMA complete

    // ---- compute: thread = 4-col strip x 8 rows, 5x8 sliding window ----
    const int ct     = tid & 63;
    const int rg     = tid >> 6;
    const int oc0    = 4 * ct;
    const int lrbase = rg * 8;

    float* outp = out + (size_t)plane * (Hn * Wn)
                      + (size_t)(r0 + rg * 8) * Wn + oc0;

    // window row = cols oc0-2..oc0+5 = pos oc0+2..oc0+9: 4x ds_read_b64
    auto ldrow = [&](int lr, float w[8]) {
        const f32x2* src = reinterpret_cast<const f32x2*>(
            &lds[lr * LSTRIDE + oc0 + 2]);           // byte 8-aligned
#pragma unroll
        for (int h = 0; h < 4; ++h) {
            f32x2 p = src[h];
            w[2 * h] = p.x; w[2 * h + 1] = p.y;
        }
    };

    float win[5][8];
#pragma unroll
    for (int i = 0; i < 4; ++i) ldrow(lrbase + i, win[i]);

#pragma unroll
    for (int k = 0; k < 8; ++k) {
        ldrow(lrbase + 4 + k, win[4]);

        f32x4 o;
#pragma unroll
        for (int j = 0; j < 4; ++j) {
            float acc = 0.f;
#pragma unroll
            for (int i = 0; i < 5; ++i)
#pragma unroll
                for (int d = 0; d < 5; ++d)
                    acc += win[i][j + d] * wf[i][d];
            o[j] = acc;
        }
        *reinterpret_cast<f32x4*>(outp + (size_t)k * Wn) = o;

#pragma unroll
        for (int i = 0; i < 4; ++i)
#pragma unroll
            for (int j = 0; j < 8; ++j) win[i][j] = win[i + 1][j];
    }
}

extern "C" void kernel_launch(void* const* d_in, const int* in_sizes, int n_in,
                              void* d_out, int out_size, void* d_ws, size_t ws_size,
                              hipStream_t stream)
{
    const float* x     = (const float*)d_in[0];
    const float* w1    = (const float*)d_in[1];
    const float* w3    = (const float*)d_in[2];
    const float* w5    = (const float*)d_in[3];
    const float* alpha = (const float*)d_in[4];
    float* out = (float*)d_out;

    omnishift_kernel<<<NWG, 256, 0, stream>>>(x, w1, w3, w5, alpha, out);
}